// Round 5
// baseline (2447.396 us; speedup 1.0000x reference)
//
#include <hip/hip_runtime.h>

// Problem constants. Established by rounds 0-4: ALL float inputs are fp32,
// output is fp32 (threshold = 2% of max|ref|; "bf16" in the harness label is
// hard-coded text). mask is int32.
#define B_   4
#define S_   1024
#define D_   512
#define H_   8
#define DH_  64
#define L_   4
#define NTOK (B_ * S_)            // 4096 tokens
#define NT   (NTOK * D_)          // 2097152 elems per activation

// ---------- bf16 helpers (used only for internal QKVR buffers) ----------
__device__ __forceinline__ float us2f(unsigned short u) {
    unsigned int v = ((unsigned int)u) << 16;
    return __uint_as_float(v);
}
__device__ __forceinline__ unsigned short f2us(float f) {
    unsigned int u = __float_as_uint(f);
    unsigned int r = (u + 0x7fffu + ((u >> 16) & 1u)) >> 16;
    return (unsigned short)r;
}
__device__ __forceinline__ void stv(float* p, float v) { *p = v; }
__device__ __forceinline__ void stv(unsigned short* p, float v) { *p = f2us(v); }

// ---------- LayerNorm: one wave per token (fp32 in, fp32 out) ----------
__global__ __launch_bounds__(256) void ln_k(const float* __restrict__ x,
                                            const float* __restrict__ w,
                                            const float* __restrict__ b,
                                            float* __restrict__ y) {
    int wv = threadIdx.x >> 6, lane = threadIdx.x & 63;
    int tok = blockIdx.x * 4 + wv;
    const float* xr = x + (size_t)tok * D_;
    float v[8];
    float s = 0.f, s2 = 0.f;
#pragma unroll
    for (int i = 0; i < 8; ++i) {
        float t = xr[lane + 64 * i];
        v[i] = t; s += t; s2 += t * t;
    }
#pragma unroll
    for (int o = 1; o < 64; o <<= 1) { s += __shfl_xor(s, o); s2 += __shfl_xor(s2, o); }
    float mu = s * (1.f / D_);
    float var = s2 * (1.f / D_) - mu * mu;
    float rs = rsqrtf(var + 1e-5f);
#pragma unroll
    for (int i = 0; i < 8; ++i) {
        int d = lane + 64 * i;
        y[(size_t)tok * D_ + d] = (v[i] - mu) * rs * w[d] + b[d];
    }
}

// ---------- fused LN2 + tanh + cubic B-spline (first 2 basis fns) -> fp32 inner ----------
__global__ __launch_bounds__(256) void kan_k(const float* __restrict__ x,
                                             const float* __restrict__ w,
                                             const float* __restrict__ b,
                                             const float* __restrict__ ic, // [D][5] fp32
                                             float* __restrict__ inner) {
    int wv = threadIdx.x >> 6, lane = threadIdx.x & 63;
    int tok = blockIdx.x * 4 + wv;
    const float* xr = x + (size_t)tok * D_;
    float v[8];
    float s = 0.f, s2 = 0.f;
#pragma unroll
    for (int i = 0; i < 8; ++i) {
        float t = xr[lane + 64 * i];
        v[i] = t; s += t; s2 += t * t;
    }
#pragma unroll
    for (int o = 1; o < 64; o <<= 1) { s += __shfl_xor(s, o); s2 += __shfl_xor(s2, o); }
    float mu = s * (1.f / D_);
    float var = s2 * (1.f / D_) - mu * mu;
    float rs = rsqrtf(var + 1e-5f);

    const float kn[8] = {-1.f,
                         -0.71428571428571430f, -0.42857142857142855f, -0.14285714285714285f,
                          0.14285714285714285f,  0.42857142857142855f,  0.71428571428571430f,
                          1.f};
#pragma unroll
    for (int i = 0; i < 8; ++i) {
        int d = lane + 64 * i;
        float zv = (v[i] - mu) * rs * w[d] + b[d];
        float xt = tanhf(zv);
        float B0[5];
#pragma unroll
        for (int k = 0; k < 5; ++k) B0[k] = (kn[k] <= xt && xt < kn[k + 1]) ? 1.f : 0.f;
        float B1[4];
#pragma unroll
        for (int k = 0; k < 4; ++k)
            B1[k] = (xt - kn[k]) / (kn[k + 1] - kn[k]) * B0[k] +
                    (kn[k + 2] - xt) / (kn[k + 2] - kn[k + 1]) * B0[k + 1];
        float B2[3];
#pragma unroll
        for (int k = 0; k < 3; ++k)
            B2[k] = (xt - kn[k]) / (kn[k + 2] - kn[k]) * B1[k] +
                    (kn[k + 3] - xt) / (kn[k + 3] - kn[k + 1]) * B1[k + 1];
        float B3[2];
#pragma unroll
        for (int k = 0; k < 2; ++k)
            B3[k] = (xt - kn[k]) / (kn[k + 3] - kn[k]) * B2[k] +
                    (kn[k + 4] - xt) / (kn[k + 4] - kn[k + 1]) * B2[k + 1];
        inner[(size_t)tok * D_ + d] = B3[0] * ic[d * 5 + 0] + B3[1] * ic[d * 5 + 1];
    }
}

// ---------- C = A @ W^T (+bias) (+res); A fp32 [4096,512], W fp32 [512,512] ----------
template <typename CT>
struct GemmArgs {
    const float* A;
    const float* W[4];
    const float* bias[4];
    const float* res;
    CT* C[4];
};

template <typename CT>
__global__ __launch_bounds__(256) void gemm_k(GemmArgs<CT> g) {
    __shared__ float As[16][68];
    __shared__ float Ws[16][68];
    int z = blockIdx.z;
    const float* W = g.W[z];
    const float* bias = g.bias[z];
    CT* C = g.C[z];
    int m0 = blockIdx.y * 64, n0 = blockIdx.x * 64;
    int t = threadIdx.x;
    int tx = t & 15, ty = t >> 4;          // 16x16 threads, 4x4 per thread
    int lr = t >> 2, lk = (t & 3) * 4;     // loader: row lr, 4 consecutive k at lk
    const float* Aptr = g.A + (size_t)(m0 + lr) * D_ + lk;
    const float* Wptr = W + (size_t)(n0 + lr) * D_ + lk;
    float acc[4][4] = {};
    for (int k0 = 0; k0 < D_; k0 += 16) {
        float4 av = *(const float4*)(Aptr + k0);
        float4 wv = *(const float4*)(Wptr + k0);
        __syncthreads();
        As[lk + 0][lr] = av.x; As[lk + 1][lr] = av.y;
        As[lk + 2][lr] = av.z; As[lk + 3][lr] = av.w;
        Ws[lk + 0][lr] = wv.x; Ws[lk + 1][lr] = wv.y;
        Ws[lk + 2][lr] = wv.z; Ws[lk + 3][lr] = wv.w;
        __syncthreads();
#pragma unroll
        for (int kk = 0; kk < 16; ++kk) {
            float4 a4 = *(const float4*)&As[kk][ty * 4];
            float4 w4 = *(const float4*)&Ws[kk][tx * 4];
            float a[4] = {a4.x, a4.y, a4.z, a4.w};
            float w_[4] = {w4.x, w4.y, w4.z, w4.w};
#pragma unroll
            for (int i = 0; i < 4; ++i)
#pragma unroll
                for (int j = 0; j < 4; ++j) acc[i][j] += a[i] * w_[j];
        }
    }
#pragma unroll
    for (int i = 0; i < 4; ++i) {
        int m = m0 + ty * 4 + i;
#pragma unroll
        for (int j = 0; j < 4; ++j) {
            int n = n0 + tx * 4 + j;
            float v = acc[i][j];
            if (bias) v += bias[n];
            if (g.res) v += g.res[(size_t)m * D_ + n];
            stv(C + (size_t)m * D_ + n, v);
        }
    }
}

// ---------- attention: block = (b,h) x 32 queries; online softmax over 64-key tiles ----------
// Q,K,V,R bf16 internal buffers; O fp32 (gated by R)
__global__ __launch_bounds__(256) void attn_k(const unsigned short* __restrict__ Q,
                                              const unsigned short* __restrict__ K,
                                              const unsigned short* __restrict__ V,
                                              const unsigned short* __restrict__ R,
                                              const int* __restrict__ mask,
                                              float* __restrict__ O) {
    __shared__ float Qs[32][68];
    __shared__ float Ks[64][68];
    __shared__ float Vs[64][68];
    __shared__ float Ps[32][68];
    int bh = blockIdx.x;
    int b = bh >> 3, h = bh & 7;
    int q0 = blockIdx.y * 32;
    int t = threadIdx.x;
    int q = t >> 3, g = t & 7;

    const unsigned short* Qrow = Q + ((size_t)(b * S_ + q0 + q) * H_ + h) * DH_;
    {
        ushort4 q1 = *(const ushort4*)(Qrow + g * 8);
        ushort4 q2 = *(const ushort4*)(Qrow + g * 8 + 4);
        Qs[q][g * 8 + 0] = us2f(q1.x); Qs[q][g * 8 + 1] = us2f(q1.y);
        Qs[q][g * 8 + 2] = us2f(q1.z); Qs[q][g * 8 + 3] = us2f(q1.w);
        Qs[q][g * 8 + 4] = us2f(q2.x); Qs[q][g * 8 + 5] = us2f(q2.y);
        Qs[q][g * 8 + 6] = us2f(q2.z); Qs[q][g * 8 + 7] = us2f(q2.w);
    }

    float m = -INFINITY, l = 0.f;
    float o[8] = {};
    int jj = t >> 2, c0 = (t & 3) * 16;

    for (int kt = 0; kt < 16; ++kt) {
        __syncthreads();
        const unsigned short* Krow = K + ((size_t)(b * S_ + kt * 64 + jj) * H_ + h) * DH_ + c0;
        const unsigned short* Vrow = V + ((size_t)(b * S_ + kt * 64 + jj) * H_ + h) * DH_ + c0;
#pragma unroll
        for (int u = 0; u < 16; u += 4) {
            ushort4 kv = *(const ushort4*)(Krow + u);
            ushort4 vv = *(const ushort4*)(Vrow + u);
            Ks[jj][c0 + u + 0] = us2f(kv.x); Ks[jj][c0 + u + 1] = us2f(kv.y);
            Ks[jj][c0 + u + 2] = us2f(kv.z); Ks[jj][c0 + u + 3] = us2f(kv.w);
            Vs[jj][c0 + u + 0] = us2f(vv.x); Vs[jj][c0 + u + 1] = us2f(vv.y);
            Vs[jj][c0 + u + 2] = us2f(vv.z); Vs[jj][c0 + u + 3] = us2f(vv.w);
        }
        __syncthreads();

        float sc[8];
        float tm = -INFINITY;
#pragma unroll
        for (int j2 = 0; j2 < 8; ++j2) {
            int j = g + j2 * 8;
            float s = 0.f;
#pragma unroll
            for (int d4 = 0; d4 < 16; ++d4) {
                float4 qv = *(const float4*)&Qs[q][d4 * 4];
                float4 kv = *(const float4*)&Ks[j][d4 * 4];
                s += qv.x * kv.x + qv.y * kv.y + qv.z * kv.z + qv.w * kv.w;
            }
            s *= 0.125f;
            if (mask[b * S_ + kt * 64 + j] == 0) s = -1e10f;
            sc[j2] = s;
            tm = fmaxf(tm, s);
        }
#pragma unroll
        for (int off = 1; off < 8; off <<= 1) tm = fmaxf(tm, __shfl_xor(tm, off));
        float mn = fmaxf(m, tm);
        float alpha = __expf(m - mn);
        float ts = 0.f;
#pragma unroll
        for (int j2 = 0; j2 < 8; ++j2) {
            float p = __expf(sc[j2] - mn);
            Ps[q][g + j2 * 8] = p;
            ts += p;
        }
#pragma unroll
        for (int off = 1; off < 8; off <<= 1) ts += __shfl_xor(ts, off);
        l = l * alpha + ts;
        m = mn;
#pragma unroll
        for (int dd = 0; dd < 8; ++dd) o[dd] *= alpha;
        __syncthreads();

        for (int j = 0; j < 64; ++j) {
            float p = Ps[q][j];
            float4 v1 = *(const float4*)&Vs[j][g * 8];
            float4 v2 = *(const float4*)&Vs[j][g * 8 + 4];
            o[0] += p * v1.x; o[1] += p * v1.y; o[2] += p * v1.z; o[3] += p * v1.w;
            o[4] += p * v2.x; o[5] += p * v2.y; o[6] += p * v2.z; o[7] += p * v2.w;
        }
    }
    float inv = 1.f / l;
    const unsigned short* Rrow = R + ((size_t)(b * S_ + q0 + q) * H_ + h) * DH_;
    float* Orow = O + ((size_t)(b * S_ + q0 + q) * H_ + h) * DH_;
#pragma unroll
    for (int dd = 0; dd < 8; ++dd)
        Orow[g * 8 + dd] = o[dd] * inv * us2f(Rrow[g * 8 + dd]);
}

extern "C" void kernel_launch(void* const* d_in, const int* in_sizes, int n_in,
                              void* d_out, int out_size, void* d_ws, size_t ws_size,
                              hipStream_t stream) {
    const float* src  = (const float*)d_in[0];
    const float* ln1w = (const float*)d_in[1];
    const float* ln1b = (const float*)d_in[2];
    const float* ln2w = (const float*)d_in[3];
    const float* ln2b = (const float*)d_in[4];
    const float* ln3w = (const float*)d_in[5];
    const float* ln3b = (const float*)d_in[6];
    const float* wq   = (const float*)d_in[7];
    const float* wqb  = (const float*)d_in[8];
    const float* wk   = (const float*)d_in[9];
    const float* wkb  = (const float*)d_in[10];
    const float* wv   = (const float*)d_in[11];
    const float* wvb  = (const float*)d_in[12];
    const float* wr   = (const float*)d_in[13];
    const float* wrb  = (const float*)d_in[14];
    const float* wo   = (const float*)d_in[15];
    const float* wob  = (const float*)d_in[16];
    const float* ic   = (const float*)d_in[17];
    const float* oc   = (const float*)d_in[18];
    const int* mask   = (const int*)d_in[19];
    float* out = (float*)d_out;   // fp32 output

    // Workspace: srcf (8MB) + zf (8MB, shared z/attn-out/inner) + QKVR bf16 (16MB) = 32MB
    float* srcf = (float*)d_ws;
    float* zf   = srcf + NT;
    unsigned short* qb = (unsigned short*)(zf + NT);
    unsigned short* kb = qb + NT;
    unsigned short* vb = kb + NT;
    unsigned short* rb = vb + NT;

    hipMemcpyAsync(srcf, src, (size_t)NT * sizeof(float), hipMemcpyDeviceToDevice, stream);

    for (int l = 0; l < L_; ++l) {
        // LN1 -> fp32 z
        ln_k<<<dim3(NTOK / 4), dim3(256), 0, stream>>>(
            srcf, ln1w + l * D_, ln1b + l * D_, zf);

        // Q,K,V,R projections (fp32 A, fp32 W, bf16 C)
        GemmArgs<unsigned short> ga;
        ga.A = zf; ga.res = nullptr;
        ga.W[0] = wq + (size_t)l * D_ * D_; ga.bias[0] = wqb + l * D_; ga.C[0] = qb;
        ga.W[1] = wk + (size_t)l * D_ * D_; ga.bias[1] = wkb + l * D_; ga.C[1] = kb;
        ga.W[2] = wv + (size_t)l * D_ * D_; ga.bias[2] = wvb + l * D_; ga.C[2] = vb;
        ga.W[3] = wr + (size_t)l * D_ * D_; ga.bias[3] = wrb + l * D_; ga.C[3] = rb;
        gemm_k<unsigned short><<<dim3(8, 64, 4), dim3(256), 0, stream>>>(ga);

        // attention + R gating -> zf (fp32; z no longer needed)
        attn_k<<<dim3(32, 32), dim3(256), 0, stream>>>(qb, kb, vb, rb, mask, zf);

        // src += zf @ Wo^T + Wo_b
        GemmArgs<float> go;
        go.A = zf; go.res = srcf;
        go.W[0] = wo + (size_t)l * D_ * D_; go.bias[0] = wob + l * D_; go.C[0] = srcf;
        go.W[1] = go.W[0]; go.bias[1] = go.bias[0]; go.C[1] = srcf;
        go.W[2] = go.W[0]; go.bias[2] = go.bias[0]; go.C[2] = srcf;
        go.W[3] = go.W[0]; go.bias[3] = go.bias[0]; go.C[3] = srcf;
        gemm_k<float><<<dim3(8, 64, 1), dim3(256), 0, stream>>>(go);

        // KAN: LN2 + tanh + spline inner -> fp32 zf
        kan_k<<<dim3(NTOK / 4), dim3(256), 0, stream>>>(
            srcf, ln2w + l * D_, ln2b + l * D_, ic + (size_t)l * D_ * 5, zf);

        // src += inner @ outer_c^T
        GemmArgs<float> gk;
        gk.A = zf; gk.res = srcf;
        gk.W[0] = oc + (size_t)l * D_ * D_; gk.bias[0] = nullptr; gk.C[0] = srcf;
        gk.W[1] = gk.W[0]; gk.bias[1] = nullptr; gk.C[1] = srcf;
        gk.W[2] = gk.W[0]; gk.bias[2] = nullptr; gk.C[2] = srcf;
        gk.W[3] = gk.W[0]; gk.bias[3] = nullptr; gk.C[3] = srcf;
        gemm_k<float><<<dim3(8, 64, 1), dim3(256), 0, stream>>>(gk);

        // LN3 (last layer writes fp32 output)
        if (l < L_ - 1)
            ln_k<<<dim3(NTOK / 4), dim3(256), 0, stream>>>(
                srcf, ln3w + l * D_, ln3b + l * D_, srcf);
        else
            ln_k<<<dim3(NTOK / 4), dim3(256), 0, stream>>>(
                srcf, ln3w + l * D_, ln3b + l * D_, out);
    }
}

// Round 6
// 1749.166 us; speedup vs baseline: 1.3992x; 1.3992x over previous
//
#include <hip/hip_runtime.h>

// Established: all float inputs fp32, output fp32, mask int32.
#define B_   4
#define S_   1024
#define D_   512
#define H_   8
#define DH_  64
#define L_   4
#define NTOK (B_ * S_)            // 4096 tokens
#define NT   (NTOK * D_)          // 2097152 elems per activation
#define DD   (D_ * D_)            // 262144 elems per weight matrix

typedef __attribute__((ext_vector_type(8))) short bf16x8;
typedef __attribute__((ext_vector_type(4))) float f32x4;

// ---------- bf16 helpers ----------
__device__ __forceinline__ float us2f(unsigned short u) {
    unsigned int v = ((unsigned int)u) << 16;
    return __uint_as_float(v);
}
__device__ __forceinline__ unsigned short f2us(float f) {
    unsigned int u = __float_as_uint(f);
    unsigned int r = (u + 0x7fffu + ((u >> 16) & 1u)) >> 16;
    return (unsigned short)r;
}
__device__ __forceinline__ void stv(float* p, float v) { *p = v; }
__device__ __forceinline__ void stv(unsigned short* p, float v) { *p = f2us(v); }

// ---------- per-layer weight fp32 -> bf16 conversion (6 matrices of DD) ----------
struct WConvArgs { const float* in[6]; };
__global__ __launch_bounds__(256) void wconv_k(WConvArgs a, unsigned short* __restrict__ out) {
    int mtx = blockIdx.y;
    int i = (blockIdx.x * 256 + threadIdx.x) * 4;
    float4 v = *(const float4*)(a.in[mtx] + i);
    ushort4 o;
    o.x = f2us(v.x); o.y = f2us(v.y); o.z = f2us(v.z); o.w = f2us(v.w);
    *(ushort4*)(out + (size_t)mtx * DD + i) = o;
}

// ---------- LayerNorm: one wave per token ----------
template <typename OutT>
__global__ __launch_bounds__(256) void ln_k(const float* __restrict__ x,
                                            const float* __restrict__ w,
                                            const float* __restrict__ b,
                                            OutT* __restrict__ y) {
    int wv = threadIdx.x >> 6, lane = threadIdx.x & 63;
    int tok = blockIdx.x * 4 + wv;
    const float* xr = x + (size_t)tok * D_;
    float v[8];
    float s = 0.f, s2 = 0.f;
#pragma unroll
    for (int i = 0; i < 8; ++i) {
        float t = xr[lane + 64 * i];
        v[i] = t; s += t; s2 += t * t;
    }
#pragma unroll
    for (int o = 1; o < 64; o <<= 1) { s += __shfl_xor(s, o); s2 += __shfl_xor(s2, o); }
    float mu = s * (1.f / D_);
    float var = s2 * (1.f / D_) - mu * mu;
    float rs = rsqrtf(var + 1e-5f);
#pragma unroll
    for (int i = 0; i < 8; ++i) {
        int d = lane + 64 * i;
        stv(y + (size_t)tok * D_ + d, (v[i] - mu) * rs * w[d] + b[d]);
    }
}

// ---------- fused LN2 + tanh + cubic B-spline -> bf16 inner ----------
__global__ __launch_bounds__(256) void kan_k(const float* __restrict__ x,
                                             const float* __restrict__ w,
                                             const float* __restrict__ b,
                                             const float* __restrict__ ic, // [D][5] fp32
                                             unsigned short* __restrict__ inner) {
    int wv = threadIdx.x >> 6, lane = threadIdx.x & 63;
    int tok = blockIdx.x * 4 + wv;
    const float* xr = x + (size_t)tok * D_;
    float v[8];
    float s = 0.f, s2 = 0.f;
#pragma unroll
    for (int i = 0; i < 8; ++i) {
        float t = xr[lane + 64 * i];
        v[i] = t; s += t; s2 += t * t;
    }
#pragma unroll
    for (int o = 1; o < 64; o <<= 1) { s += __shfl_xor(s, o); s2 += __shfl_xor(s2, o); }
    float mu = s * (1.f / D_);
    float var = s2 * (1.f / D_) - mu * mu;
    float rs = rsqrtf(var + 1e-5f);

    const float kn[8] = {-1.f,
                         -0.71428571428571430f, -0.42857142857142855f, -0.14285714285714285f,
                          0.14285714285714285f,  0.42857142857142855f,  0.71428571428571430f,
                          1.f};
#pragma unroll
    for (int i = 0; i < 8; ++i) {
        int d = lane + 64 * i;
        float zv = (v[i] - mu) * rs * w[d] + b[d];
        float xt = tanhf(zv);
        float B0[5];
#pragma unroll
        for (int k = 0; k < 5; ++k) B0[k] = (kn[k] <= xt && xt < kn[k + 1]) ? 1.f : 0.f;
        float B1[4];
#pragma unroll
        for (int k = 0; k < 4; ++k)
            B1[k] = (xt - kn[k]) / (kn[k + 1] - kn[k]) * B0[k] +
                    (kn[k + 2] - xt) / (kn[k + 2] - kn[k + 1]) * B0[k + 1];
        float B2[3];
#pragma unroll
        for (int k = 0; k < 3; ++k)
            B2[k] = (xt - kn[k]) / (kn[k + 2] - kn[k]) * B1[k] +
                    (kn[k + 3] - xt) / (kn[k + 3] - kn[k + 1]) * B1[k + 1];
        float B3[2];
#pragma unroll
        for (int k = 0; k < 2; ++k)
            B3[k] = (xt - kn[k]) / (kn[k + 3] - kn[k]) * B2[k] +
                    (kn[k + 4] - xt) / (kn[k + 4] - kn[k + 1]) * B2[k + 1];
        inner[(size_t)tok * D_ + d] = f2us(B3[0] * ic[d * 5 + 0] + B3[1] * ic[d * 5 + 1]);
    }
}

// ---------- MFMA GEMM: C = A @ W^T (+bias) (+res) ----------
// A bf16 [4096,512] row-major; W bf16 [512,512] row-major (n rows, k contiguous).
// Block 64x64, 4 waves of 32x32, 2x2 mfma_f32_16x16x32_bf16 tiles, BK=32.
template <typename CT>
struct MGemmArgs {
    const unsigned short* A;
    const unsigned short* W[4];
    const float* bias[4];
    const float* res;
    CT* C[4];
};

template <typename CT>
__global__ __launch_bounds__(256) void mgemm_k(MGemmArgs<CT> g) {
    // stride 40 bf16 = 80 B = 20 banks: consecutive rows 2-way bank alias (free, m136)
    __shared__ unsigned short As[64][40];
    __shared__ unsigned short Bs[64][40];
    int z = blockIdx.z;
    const unsigned short* W = g.W[z];
    const float* bias = g.bias[z];
    CT* C = g.C[z];
    int m0 = blockIdx.y * 64, n0 = blockIdx.x * 64;
    int t = threadIdx.x;
    int wave = t >> 6, lane = t & 63;
    int wm = (wave >> 1) * 32, wn = (wave & 1) * 32;   // wave tile origin
    int lrow = t >> 2, lk = (t & 3) * 8;               // loader: 64 rows x 4 chunks of 8 bf16
    const unsigned short* Ag = g.A + (size_t)(m0 + lrow) * D_ + lk;
    const unsigned short* Wg = W + (size_t)(n0 + lrow) * D_ + lk;

    f32x4 acc[2][2];
#pragma unroll
    for (int i = 0; i < 2; ++i)
#pragma unroll
        for (int j = 0; j < 2; ++j)
#pragma unroll
            for (int r = 0; r < 4; ++r) acc[i][j][r] = 0.f;

    int fm = lane & 15, fq = (lane >> 4) * 8;   // frag row within tile, k-offset

    for (int k0 = 0; k0 < D_; k0 += 32) {
        uint4 a = *(const uint4*)(Ag + k0);
        uint4 b = *(const uint4*)(Wg + k0);
        __syncthreads();
        *(uint4*)&As[lrow][lk] = a;
        *(uint4*)&Bs[lrow][lk] = b;
        __syncthreads();
        bf16x8 a0 = *(const bf16x8*)&As[wm + fm][fq];
        bf16x8 a1 = *(const bf16x8*)&As[wm + 16 + fm][fq];
        bf16x8 b0 = *(const bf16x8*)&Bs[wn + fm][fq];
        bf16x8 b1 = *(const bf16x8*)&Bs[wn + 16 + fm][fq];
        acc[0][0] = __builtin_amdgcn_mfma_f32_16x16x32_bf16(a0, b0, acc[0][0], 0, 0, 0);
        acc[0][1] = __builtin_amdgcn_mfma_f32_16x16x32_bf16(a0, b1, acc[0][1], 0, 0, 0);
        acc[1][0] = __builtin_amdgcn_mfma_f32_16x16x32_bf16(a1, b0, acc[1][0], 0, 0, 0);
        acc[1][1] = __builtin_amdgcn_mfma_f32_16x16x32_bf16(a1, b1, acc[1][1], 0, 0, 0);
    }

    // C/D layout: col = lane&15, row = (lane>>4)*4 + reg   [verified m89/m91]
    int col = lane & 15, rbase = (lane >> 4) * 4;
#pragma unroll
    for (int i = 0; i < 2; ++i)
#pragma unroll
        for (int j = 0; j < 2; ++j) {
            int n = n0 + wn + j * 16 + col;
            float bv = bias ? bias[n] : 0.f;
#pragma unroll
            for (int r = 0; r < 4; ++r) {
                int m = m0 + wm + i * 16 + rbase + r;
                float v = acc[i][j][r] + bv;
                if (g.res) v += g.res[(size_t)m * D_ + n];
                stv(C + (size_t)m * D_ + n, v);
            }
        }
}

// ---------- attention: block = (b,h) x 32 queries; online softmax over 64-key tiles ----------
// Q,K,V,R bf16; O bf16 (gated by R). Unchanged from round 5 except bf16 output.
__global__ __launch_bounds__(256) void attn_k(const unsigned short* __restrict__ Q,
                                              const unsigned short* __restrict__ K,
                                              const unsigned short* __restrict__ V,
                                              const unsigned short* __restrict__ R,
                                              const int* __restrict__ mask,
                                              unsigned short* __restrict__ O) {
    __shared__ float Qs[32][68];
    __shared__ float Ks[64][68];
    __shared__ float Vs[64][68];
    __shared__ float Ps[32][68];
    int bh = blockIdx.x;
    int b = bh >> 3, h = bh & 7;
    int q0 = blockIdx.y * 32;
    int t = threadIdx.x;
    int q = t >> 3, g = t & 7;

    const unsigned short* Qrow = Q + ((size_t)(b * S_ + q0 + q) * H_ + h) * DH_;
    {
        ushort4 q1 = *(const ushort4*)(Qrow + g * 8);
        ushort4 q2 = *(const ushort4*)(Qrow + g * 8 + 4);
        Qs[q][g * 8 + 0] = us2f(q1.x); Qs[q][g * 8 + 1] = us2f(q1.y);
        Qs[q][g * 8 + 2] = us2f(q1.z); Qs[q][g * 8 + 3] = us2f(q1.w);
        Qs[q][g * 8 + 4] = us2f(q2.x); Qs[q][g * 8 + 5] = us2f(q2.y);
        Qs[q][g * 8 + 6] = us2f(q2.z); Qs[q][g * 8 + 7] = us2f(q2.w);
    }

    float m = -INFINITY, l = 0.f;
    float o[8] = {};
    int jj = t >> 2, c0 = (t & 3) * 16;

    for (int kt = 0; kt < 16; ++kt) {
        __syncthreads();
        const unsigned short* Krow = K + ((size_t)(b * S_ + kt * 64 + jj) * H_ + h) * DH_ + c0;
        const unsigned short* Vrow = V + ((size_t)(b * S_ + kt * 64 + jj) * H_ + h) * DH_ + c0;
#pragma unroll
        for (int u = 0; u < 16; u += 4) {
            ushort4 kv = *(const ushort4*)(Krow + u);
            ushort4 vv = *(const ushort4*)(Vrow + u);
            Ks[jj][c0 + u + 0] = us2f(kv.x); Ks[jj][c0 + u + 1] = us2f(kv.y);
            Ks[jj][c0 + u + 2] = us2f(kv.z); Ks[jj][c0 + u + 3] = us2f(kv.w);
            Vs[jj][c0 + u + 0] = us2f(vv.x); Vs[jj][c0 + u + 1] = us2f(vv.y);
            Vs[jj][c0 + u + 2] = us2f(vv.z); Vs[jj][c0 + u + 3] = us2f(vv.w);
        }
        __syncthreads();

        float sc[8];
        float tm = -INFINITY;
#pragma unroll
        for (int j2 = 0; j2 < 8; ++j2) {
            int j = g + j2 * 8;
            float s = 0.f;
#pragma unroll
            for (int d4 = 0; d4 < 16; ++d4) {
                float4 qv = *(const float4*)&Qs[q][d4 * 4];
                float4 kv = *(const float4*)&Ks[j][d4 * 4];
                s += qv.x * kv.x + qv.y * kv.y + qv.z * kv.z + qv.w * kv.w;
            }
            s *= 0.125f;
            if (mask[b * S_ + kt * 64 + j] == 0) s = -1e10f;
            sc[j2] = s;
            tm = fmaxf(tm, s);
        }
#pragma unroll
        for (int off = 1; off < 8; off <<= 1) tm = fmaxf(tm, __shfl_xor(tm, off));
        float mn = fmaxf(m, tm);
        float alpha = __expf(m - mn);
        float ts = 0.f;
#pragma unroll
        for (int j2 = 0; j2 < 8; ++j2) {
            float p = __expf(sc[j2] - mn);
            Ps[q][g + j2 * 8] = p;
            ts += p;
        }
#pragma unroll
        for (int off = 1; off < 8; off <<= 1) ts += __shfl_xor(ts, off);
        l = l * alpha + ts;
        m = mn;
#pragma unroll
        for (int dd = 0; dd < 8; ++dd) o[dd] *= alpha;
        __syncthreads();

        for (int j = 0; j < 64; ++j) {
            float p = Ps[q][j];
            float4 v1 = *(const float4*)&Vs[j][g * 8];
            float4 v2 = *(const float4*)&Vs[j][g * 8 + 4];
            o[0] += p * v1.x; o[1] += p * v1.y; o[2] += p * v1.z; o[3] += p * v1.w;
            o[4] += p * v2.x; o[5] += p * v2.y; o[6] += p * v2.z; o[7] += p * v2.w;
        }
    }
    float inv = 1.f / l;
    const unsigned short* Rrow = R + ((size_t)(b * S_ + q0 + q) * H_ + h) * DH_;
    unsigned short* Orow = O + ((size_t)(b * S_ + q0 + q) * H_ + h) * DH_;
#pragma unroll
    for (int dd = 0; dd < 8; ++dd)
        Orow[g * 8 + dd] = f2us(o[dd] * inv * us2f(Rrow[g * 8 + dd]));
}

extern "C" void kernel_launch(void* const* d_in, const int* in_sizes, int n_in,
                              void* d_out, int out_size, void* d_ws, size_t ws_size,
                              hipStream_t stream) {
    const float* src  = (const float*)d_in[0];
    const float* ln1w = (const float*)d_in[1];
    const float* ln1b = (const float*)d_in[2];
    const float* ln2w = (const float*)d_in[3];
    const float* ln2b = (const float*)d_in[4];
    const float* ln3w = (const float*)d_in[5];
    const float* ln3b = (const float*)d_in[6];
    const float* wq   = (const float*)d_in[7];
    const float* wqb  = (const float*)d_in[8];
    const float* wk   = (const float*)d_in[9];
    const float* wkb  = (const float*)d_in[10];
    const float* wv   = (const float*)d_in[11];
    const float* wvb  = (const float*)d_in[12];
    const float* wr   = (const float*)d_in[13];
    const float* wrb  = (const float*)d_in[14];
    const float* wo   = (const float*)d_in[15];
    const float* wob  = (const float*)d_in[16];
    const float* ic   = (const float*)d_in[17];
    const float* oc   = (const float*)d_in[18];
    const int* mask   = (const int*)d_in[19];
    float* out = (float*)d_out;

    // Workspace: srcf fp32 8MB | zb bf16 4MB | qkvr bf16 16MB | cw bf16 3MB = 31MB
    float* srcf = (float*)d_ws;
    unsigned short* zb = (unsigned short*)(srcf + NT);   // z / attn-out / inner (reused)
    unsigned short* qb = zb + NT;
    unsigned short* kb = qb + NT;
    unsigned short* vb = kb + NT;
    unsigned short* rb = vb + NT;
    unsigned short* cw = rb + NT;   // 6 bf16 weight matrices for current layer
    unsigned short* cwq = cw + 0 * DD;
    unsigned short* cwk = cw + 1 * DD;
    unsigned short* cwv = cw + 2 * DD;
    unsigned short* cwr = cw + 3 * DD;
    unsigned short* cwo = cw + 4 * DD;
    unsigned short* coc = cw + 5 * DD;

    hipMemcpyAsync(srcf, src, (size_t)NT * sizeof(float), hipMemcpyDeviceToDevice, stream);

    for (int l = 0; l < L_; ++l) {
        // convert this layer's 6 weight matrices to bf16
        WConvArgs wc;
        wc.in[0] = wq + (size_t)l * DD; wc.in[1] = wk + (size_t)l * DD;
        wc.in[2] = wv + (size_t)l * DD; wc.in[3] = wr + (size_t)l * DD;
        wc.in[4] = wo + (size_t)l * DD; wc.in[5] = oc + (size_t)l * DD;
        wconv_k<<<dim3(DD / 1024, 6), dim3(256), 0, stream>>>(wc, cw);

        // LN1 -> bf16 z
        ln_k<unsigned short><<<dim3(NTOK / 4), dim3(256), 0, stream>>>(
            srcf, ln1w + l * D_, ln1b + l * D_, zb);

        // Q,K,V,R projections (MFMA)
        MGemmArgs<unsigned short> ga;
        ga.A = zb; ga.res = nullptr;
        ga.W[0] = cwq; ga.bias[0] = wqb + l * D_; ga.C[0] = qb;
        ga.W[1] = cwk; ga.bias[1] = wkb + l * D_; ga.C[1] = kb;
        ga.W[2] = cwv; ga.bias[2] = wvb + l * D_; ga.C[2] = vb;
        ga.W[3] = cwr; ga.bias[3] = wrb + l * D_; ga.C[3] = rb;
        mgemm_k<unsigned short><<<dim3(8, 64, 4), dim3(256), 0, stream>>>(ga);

        // attention + R gating -> zb (bf16)
        attn_k<<<dim3(32, 32), dim3(256), 0, stream>>>(qb, kb, vb, rb, mask, zb);

        // src += zb @ Wo^T + Wo_b  (MFMA)
        MGemmArgs<float> go;
        go.A = zb; go.res = srcf;
        go.W[0] = cwo; go.bias[0] = wob + l * D_; go.C[0] = srcf;
        go.W[1] = go.W[0]; go.bias[1] = go.bias[0]; go.C[1] = srcf;
        go.W[2] = go.W[0]; go.bias[2] = go.bias[0]; go.C[2] = srcf;
        go.W[3] = go.W[0]; go.bias[3] = go.bias[0]; go.C[3] = srcf;
        mgemm_k<float><<<dim3(8, 64, 1), dim3(256), 0, stream>>>(go);

        // KAN: LN2 + tanh + spline inner -> bf16 zb
        kan_k<<<dim3(NTOK / 4), dim3(256), 0, stream>>>(
            srcf, ln2w + l * D_, ln2b + l * D_, ic + (size_t)l * D_ * 5, zb);

        // src += inner @ outer_c^T  (MFMA)
        MGemmArgs<float> gk;
        gk.A = zb; gk.res = srcf;
        gk.W[0] = coc; gk.bias[0] = nullptr; gk.C[0] = srcf;
        gk.W[1] = gk.W[0]; gk.bias[1] = nullptr; gk.C[1] = srcf;
        gk.W[2] = gk.W[0]; gk.bias[2] = nullptr; gk.C[2] = srcf;
        gk.W[3] = gk.W[0]; gk.bias[3] = nullptr; gk.C[3] = srcf;
        mgemm_k<float><<<dim3(8, 64, 1), dim3(256), 0, stream>>>(gk);

        // LN3 (last layer writes fp32 output)
        if (l < L_ - 1)
            ln_k<float><<<dim3(NTOK / 4), dim3(256), 0, stream>>>(
                srcf, ln3w + l * D_, ln3b + l * D_, srcf);
        else
            ln_k<float><<<dim3(NTOK / 4), dim3(256), 0, stream>>>(
                srcf, ln3w + l * D_, ln3b + l * D_, out);
    }
}

// Round 7
// 595.771 us; speedup vs baseline: 4.1079x; 2.9360x over previous
//
#include <hip/hip_runtime.h>

// Established: all float inputs fp32, output fp32, mask int32.
#define B_   4
#define S_   1024
#define D_   512
#define H_   8
#define DH_  64
#define L_   4
#define NTOK (B_ * S_)            // 4096 tokens
#define NT   (NTOK * D_)          // 2097152 elems per activation
#define DD   (D_ * D_)            // 262144 elems per weight matrix

typedef __attribute__((ext_vector_type(8))) short bf16x8;
typedef __attribute__((ext_vector_type(4))) float f32x4;

// ---------- bf16 helpers ----------
__device__ __forceinline__ float us2f(unsigned short u) {
    unsigned int v = ((unsigned int)u) << 16;
    return __uint_as_float(v);
}
__device__ __forceinline__ unsigned short f2us(float f) {
    unsigned int u = __float_as_uint(f);
    unsigned int r = (u + 0x7fffu + ((u >> 16) & 1u)) >> 16;
    return (unsigned short)r;
}
__device__ __forceinline__ void stv(float* p, float v) { *p = v; }
__device__ __forceinline__ void stv(unsigned short* p, float v) { *p = f2us(v); }

// ---------- per-layer weight fp32 -> bf16 conversion (6 matrices of DD) ----------
struct WConvArgs { const float* in[6]; };
__global__ __launch_bounds__(256) void wconv_k(WConvArgs a, unsigned short* __restrict__ out) {
    int mtx = blockIdx.y;
    int i = (blockIdx.x * 256 + threadIdx.x) * 4;
    float4 v = *(const float4*)(a.in[mtx] + i);
    ushort4 o;
    o.x = f2us(v.x); o.y = f2us(v.y); o.z = f2us(v.z); o.w = f2us(v.w);
    *(ushort4*)(out + (size_t)mtx * DD + i) = o;
}

// ---------- LayerNorm: one wave per token ----------
template <typename OutT>
__global__ __launch_bounds__(256) void ln_k(const float* __restrict__ x,
                                            const float* __restrict__ w,
                                            const float* __restrict__ b,
                                            OutT* __restrict__ y) {
    int wv = threadIdx.x >> 6, lane = threadIdx.x & 63;
    int tok = blockIdx.x * 4 + wv;
    const float* xr = x + (size_t)tok * D_;
    float v[8];
    float s = 0.f, s2 = 0.f;
#pragma unroll
    for (int i = 0; i < 8; ++i) {
        float t = xr[lane + 64 * i];
        v[i] = t; s += t; s2 += t * t;
    }
#pragma unroll
    for (int o = 1; o < 64; o <<= 1) { s += __shfl_xor(s, o); s2 += __shfl_xor(s2, o); }
    float mu = s * (1.f / D_);
    float var = s2 * (1.f / D_) - mu * mu;
    float rs = rsqrtf(var + 1e-5f);
#pragma unroll
    for (int i = 0; i < 8; ++i) {
        int d = lane + 64 * i;
        stv(y + (size_t)tok * D_ + d, (v[i] - mu) * rs * w[d] + b[d]);
    }
}

// ---------- fused LN2 + tanh + cubic B-spline -> bf16 inner ----------
__global__ __launch_bounds__(256) void kan_k(const float* __restrict__ x,
                                             const float* __restrict__ w,
                                             const float* __restrict__ b,
                                             const float* __restrict__ ic, // [D][5] fp32
                                             unsigned short* __restrict__ inner) {
    int wv = threadIdx.x >> 6, lane = threadIdx.x & 63;
    int tok = blockIdx.x * 4 + wv;
    const float* xr = x + (size_t)tok * D_;
    float v[8];
    float s = 0.f, s2 = 0.f;
#pragma unroll
    for (int i = 0; i < 8; ++i) {
        float t = xr[lane + 64 * i];
        v[i] = t; s += t; s2 += t * t;
    }
#pragma unroll
    for (int o = 1; o < 64; o <<= 1) { s += __shfl_xor(s, o); s2 += __shfl_xor(s2, o); }
    float mu = s * (1.f / D_);
    float var = s2 * (1.f / D_) - mu * mu;
    float rs = rsqrtf(var + 1e-5f);

    const float kn[8] = {-1.f,
                         -0.71428571428571430f, -0.42857142857142855f, -0.14285714285714285f,
                          0.14285714285714285f,  0.42857142857142855f,  0.71428571428571430f,
                          1.f};
#pragma unroll
    for (int i = 0; i < 8; ++i) {
        int d = lane + 64 * i;
        float zv = (v[i] - mu) * rs * w[d] + b[d];
        float xt = tanhf(zv);
        float B0[5];
#pragma unroll
        for (int k = 0; k < 5; ++k) B0[k] = (kn[k] <= xt && xt < kn[k + 1]) ? 1.f : 0.f;
        float B1[4];
#pragma unroll
        for (int k = 0; k < 4; ++k)
            B1[k] = (xt - kn[k]) / (kn[k + 1] - kn[k]) * B0[k] +
                    (kn[k + 2] - xt) / (kn[k + 2] - kn[k + 1]) * B0[k + 1];
        float B2[3];
#pragma unroll
        for (int k = 0; k < 3; ++k)
            B2[k] = (xt - kn[k]) / (kn[k + 2] - kn[k]) * B1[k] +
                    (kn[k + 3] - xt) / (kn[k + 3] - kn[k + 1]) * B1[k + 1];
        float B3[2];
#pragma unroll
        for (int k = 0; k < 2; ++k)
            B3[k] = (xt - kn[k]) / (kn[k + 3] - kn[k]) * B2[k] +
                    (kn[k + 4] - xt) / (kn[k + 4] - kn[k + 1]) * B2[k + 1];
        inner[(size_t)tok * D_ + d] = f2us(B3[0] * ic[d * 5 + 0] + B3[1] * ic[d * 5 + 1]);
    }
}

// ---------- MFMA GEMM: C = A @ W^T (+bias) (+res) ----------
template <typename CT>
struct MGemmArgs {
    const unsigned short* A;
    const unsigned short* W[4];
    const float* bias[4];
    const float* res;
    CT* C[4];
};

template <typename CT>
__global__ __launch_bounds__(256) void mgemm_k(MGemmArgs<CT> g) {
    __shared__ unsigned short As[64][40];
    __shared__ unsigned short Bs[64][40];
    int z = blockIdx.z;
    const unsigned short* W = g.W[z];
    const float* bias = g.bias[z];
    CT* C = g.C[z];
    int m0 = blockIdx.y * 64, n0 = blockIdx.x * 64;
    int t = threadIdx.x;
    int wave = t >> 6, lane = t & 63;
    int wm = (wave >> 1) * 32, wn = (wave & 1) * 32;
    int lrow = t >> 2, lk = (t & 3) * 8;
    const unsigned short* Ag = g.A + (size_t)(m0 + lrow) * D_ + lk;
    const unsigned short* Wg = W + (size_t)(n0 + lrow) * D_ + lk;

    f32x4 acc[2][2];
#pragma unroll
    for (int i = 0; i < 2; ++i)
#pragma unroll
        for (int j = 0; j < 2; ++j)
#pragma unroll
            for (int r = 0; r < 4; ++r) acc[i][j][r] = 0.f;

    int fm = lane & 15, fq = (lane >> 4) * 8;

    for (int k0 = 0; k0 < D_; k0 += 32) {
        uint4 a = *(const uint4*)(Ag + k0);
        uint4 b = *(const uint4*)(Wg + k0);
        __syncthreads();
        *(uint4*)&As[lrow][lk] = a;
        *(uint4*)&Bs[lrow][lk] = b;
        __syncthreads();
        bf16x8 a0 = *(const bf16x8*)&As[wm + fm][fq];
        bf16x8 a1 = *(const bf16x8*)&As[wm + 16 + fm][fq];
        bf16x8 b0 = *(const bf16x8*)&Bs[wn + fm][fq];
        bf16x8 b1 = *(const bf16x8*)&Bs[wn + 16 + fm][fq];
        acc[0][0] = __builtin_amdgcn_mfma_f32_16x16x32_bf16(a0, b0, acc[0][0], 0, 0, 0);
        acc[0][1] = __builtin_amdgcn_mfma_f32_16x16x32_bf16(a0, b1, acc[0][1], 0, 0, 0);
        acc[1][0] = __builtin_amdgcn_mfma_f32_16x16x32_bf16(a1, b0, acc[1][0], 0, 0, 0);
        acc[1][1] = __builtin_amdgcn_mfma_f32_16x16x32_bf16(a1, b1, acc[1][1], 0, 0, 0);
    }

    int col = lane & 15, rbase = (lane >> 4) * 4;
#pragma unroll
    for (int i = 0; i < 2; ++i)
#pragma unroll
        for (int j = 0; j < 2; ++j) {
            int n = n0 + wn + j * 16 + col;
            float bv = bias ? bias[n] : 0.f;
#pragma unroll
            for (int r = 0; r < 4; ++r) {
                int m = m0 + wm + i * 16 + rbase + r;
                float v = acc[i][j][r] + bv;
                if (g.res) v += g.res[(size_t)m * D_ + n];
                stv(C + (size_t)m * D_ + n, v);
            }
        }
}

// ---------- MFMA flash attention ----------
// Block = (b,h) x 64 queries; 4 waves x 16 queries. K-tiles of 64 keys.
// mfma(a=Xrows, b=Yrows) = X @ Y^T; C-layout col=lane&15, row=(lane>>4)*4+reg.
__global__ __launch_bounds__(256) void attn_k(const unsigned short* __restrict__ Q,
                                              const unsigned short* __restrict__ K,
                                              const unsigned short* __restrict__ V,
                                              const unsigned short* __restrict__ R,
                                              const int* __restrict__ mask,
                                              unsigned short* __restrict__ O) {
    // stride 72 bf16 = 144 B (16B-aligned rows, 2-way-free banking on b128 reads)
    __shared__ unsigned short Ks[64][72];
    __shared__ unsigned short Vt[64][72];   // V transposed: Vt[d][j]
    __shared__ unsigned short Ps[4][16][72]; // per-wave P round-trip
    __shared__ float Ms[64];                 // additive mask for this key tile

    int bh = blockIdx.x;
    int b = bh >> 3, h = bh & 7;
    int qt0 = blockIdx.y * 64;
    int t = threadIdx.x, wave = t >> 6, lane = t & 63;
    int l15 = lane & 15, quad = lane >> 4;
    int qw0 = qt0 + wave * 16;              // this wave's 16 queries

    // Q A-fragments straight from global (rows q, k contiguous)
    const unsigned short* Qrow = Q + ((size_t)(b * S_ + qw0 + l15) * H_ + h) * DH_;
    bf16x8 qf[2];
    qf[0] = *(const bf16x8*)(Qrow + quad * 8);
    qf[1] = *(const bf16x8*)(Qrow + 32 + quad * 8);

    float m_i[4], l_i[4];
    f32x4 acc_o[4];
#pragma unroll
    for (int r = 0; r < 4; ++r) { m_i[r] = -INFINITY; l_i[r] = 0.f; }
#pragma unroll
    for (int dt = 0; dt < 4; ++dt)
#pragma unroll
        for (int r = 0; r < 4; ++r) acc_o[dt][r] = 0.f;

    int jrow = t >> 2, c0 = (t & 3) * 16;   // staging map: 64 rows x 4 chunks of 16

    for (int kt = 0; kt < 16; ++kt) {
        __syncthreads();   // all waves done with previous Ks/Vt
        {
            int jg = kt * 64 + jrow;
            const unsigned short* kr = K + ((size_t)(b * S_ + jg) * H_ + h) * DH_ + c0;
            const unsigned short* vr = V + ((size_t)(b * S_ + jg) * H_ + h) * DH_ + c0;
            uint4 k1 = *(const uint4*)kr;
            uint4 k2 = *(const uint4*)(kr + 8);
            *(uint4*)&Ks[jrow][c0] = k1;
            *(uint4*)&Ks[jrow][c0 + 8] = k2;
            unsigned short vv[16];
            *(uint4*)&vv[0] = *(const uint4*)vr;
            *(uint4*)&vv[8] = *(const uint4*)(vr + 8);
#pragma unroll
            for (int u = 0; u < 16; ++u) Vt[c0 + u][jrow] = vv[u];
            if (t < 64) Ms[t] = mask[b * S_ + kt * 64 + t] ? 0.f : -1e10f;
        }
        __syncthreads();

        // scores: S = Q @ K^T  (per wave: 16q x 64j)
        f32x4 accs[4];
#pragma unroll
        for (int jt = 0; jt < 4; ++jt)
#pragma unroll
            for (int r = 0; r < 4; ++r) accs[jt][r] = 0.f;
#pragma unroll
        for (int kc = 0; kc < 2; ++kc) {
#pragma unroll
            for (int jt = 0; jt < 4; ++jt) {
                bf16x8 kf = *(const bf16x8*)&Ks[jt * 16 + l15][kc * 32 + quad * 8];
                accs[jt] = __builtin_amdgcn_mfma_f32_16x16x32_bf16(qf[kc], kf, accs[jt], 0, 0, 0);
            }
        }

        // online softmax (rows = quad*4+r, cols = jt*16 + l15)
        float s[4][4];
        float rm[4] = {-INFINITY, -INFINITY, -INFINITY, -INFINITY};
#pragma unroll
        for (int jt = 0; jt < 4; ++jt) {
            float madd = Ms[jt * 16 + l15];
#pragma unroll
            for (int r = 0; r < 4; ++r) {
                float sv = accs[jt][r] * 0.125f + madd;
                s[jt][r] = sv;
                rm[r] = fmaxf(rm[r], sv);
            }
        }
#pragma unroll
        for (int off = 1; off < 16; off <<= 1)
#pragma unroll
            for (int r = 0; r < 4; ++r) rm[r] = fmaxf(rm[r], __shfl_xor(rm[r], off));

        float alpha[4], lad[4] = {0.f, 0.f, 0.f, 0.f};
#pragma unroll
        for (int r = 0; r < 4; ++r) {
            float mn = fmaxf(m_i[r], rm[r]);
            alpha[r] = __expf(m_i[r] - mn);   // exp(-inf)=0 first tile
            m_i[r] = mn;
        }
#pragma unroll
        for (int jt = 0; jt < 4; ++jt)
#pragma unroll
            for (int r = 0; r < 4; ++r) {
                float p = __expf(s[jt][r] - m_i[r]);
                s[jt][r] = p;
                lad[r] += p;
            }
#pragma unroll
        for (int off = 1; off < 16; off <<= 1)
#pragma unroll
            for (int r = 0; r < 4; ++r) lad[r] += __shfl_xor(lad[r], off);
#pragma unroll
        for (int r = 0; r < 4; ++r) l_i[r] = l_i[r] * alpha[r] + lad[r];
#pragma unroll
        for (int dt = 0; dt < 4; ++dt)
#pragma unroll
            for (int r = 0; r < 4; ++r) acc_o[dt][r] *= alpha[r];

        // P: C-layout -> LDS -> A-layout (per-wave region; no barrier needed)
#pragma unroll
        for (int jt = 0; jt < 4; ++jt)
#pragma unroll
            for (int r = 0; r < 4; ++r)
                Ps[wave][quad * 4 + r][jt * 16 + l15] = f2us(s[jt][r]);

        // O += P @ V   (b-frags from Vt rows = dims)
#pragma unroll
        for (int kc = 0; kc < 2; ++kc) {
            bf16x8 pf = *(const bf16x8*)&Ps[wave][l15][kc * 32 + quad * 8];
#pragma unroll
            for (int dt = 0; dt < 4; ++dt) {
                bf16x8 vf = *(const bf16x8*)&Vt[dt * 16 + l15][kc * 32 + quad * 8];
                acc_o[dt] = __builtin_amdgcn_mfma_f32_16x16x32_bf16(pf, vf, acc_o[dt], 0, 0, 0);
            }
        }
    }

    // epilogue: normalize, gate by R, store bf16
#pragma unroll
    for (int r = 0; r < 4; ++r) {
        int q = qw0 + quad * 4 + r;
        float inv = 1.f / l_i[r];
        const unsigned short* Rr = R + ((size_t)(b * S_ + q) * H_ + h) * DH_;
        unsigned short* Or = O + ((size_t)(b * S_ + q) * H_ + h) * DH_;
#pragma unroll
        for (int dt = 0; dt < 4; ++dt) {
            int d = dt * 16 + l15;
            Or[d] = f2us(acc_o[dt][r] * inv * us2f(Rr[d]));
        }
    }
}

extern "C" void kernel_launch(void* const* d_in, const int* in_sizes, int n_in,
                              void* d_out, int out_size, void* d_ws, size_t ws_size,
                              hipStream_t stream) {
    const float* src  = (const float*)d_in[0];
    const float* ln1w = (const float*)d_in[1];
    const float* ln1b = (const float*)d_in[2];
    const float* ln2w = (const float*)d_in[3];
    const float* ln2b = (const float*)d_in[4];
    const float* ln3w = (const float*)d_in[5];
    const float* ln3b = (const float*)d_in[6];
    const float* wq   = (const float*)d_in[7];
    const float* wqb  = (const float*)d_in[8];
    const float* wk   = (const float*)d_in[9];
    const float* wkb  = (const float*)d_in[10];
    const float* wv   = (const float*)d_in[11];
    const float* wvb  = (const float*)d_in[12];
    const float* wr   = (const float*)d_in[13];
    const float* wrb  = (const float*)d_in[14];
    const float* wo   = (const float*)d_in[15];
    const float* wob  = (const float*)d_in[16];
    const float* ic   = (const float*)d_in[17];
    const float* oc   = (const float*)d_in[18];
    const int* mask   = (const int*)d_in[19];
    float* out = (float*)d_out;

    // Workspace: srcf fp32 8MB | zb bf16 4MB | qkvr bf16 16MB | cw bf16 3MB = 31MB
    float* srcf = (float*)d_ws;
    unsigned short* zb = (unsigned short*)(srcf + NT);
    unsigned short* qb = zb + NT;
    unsigned short* kb = qb + NT;
    unsigned short* vb = kb + NT;
    unsigned short* rb = vb + NT;
    unsigned short* cw = rb + NT;
    unsigned short* cwq = cw + 0 * DD;
    unsigned short* cwk = cw + 1 * DD;
    unsigned short* cwv = cw + 2 * DD;
    unsigned short* cwr = cw + 3 * DD;
    unsigned short* cwo = cw + 4 * DD;
    unsigned short* coc = cw + 5 * DD;

    hipMemcpyAsync(srcf, src, (size_t)NT * sizeof(float), hipMemcpyDeviceToDevice, stream);

    for (int l = 0; l < L_; ++l) {
        WConvArgs wc;
        wc.in[0] = wq + (size_t)l * DD; wc.in[1] = wk + (size_t)l * DD;
        wc.in[2] = wv + (size_t)l * DD; wc.in[3] = wr + (size_t)l * DD;
        wc.in[4] = wo + (size_t)l * DD; wc.in[5] = oc + (size_t)l * DD;
        wconv_k<<<dim3(DD / 1024, 6), dim3(256), 0, stream>>>(wc, cw);

        ln_k<unsigned short><<<dim3(NTOK / 4), dim3(256), 0, stream>>>(
            srcf, ln1w + l * D_, ln1b + l * D_, zb);

        MGemmArgs<unsigned short> ga;
        ga.A = zb; ga.res = nullptr;
        ga.W[0] = cwq; ga.bias[0] = wqb + l * D_; ga.C[0] = qb;
        ga.W[1] = cwk; ga.bias[1] = wkb + l * D_; ga.C[1] = kb;
        ga.W[2] = cwv; ga.bias[2] = wvb + l * D_; ga.C[2] = vb;
        ga.W[3] = cwr; ga.bias[3] = wrb + l * D_; ga.C[3] = rb;
        mgemm_k<unsigned short><<<dim3(8, 64, 4), dim3(256), 0, stream>>>(ga);

        // MFMA flash attention + R gating -> zb (bf16)
        attn_k<<<dim3(32, 16), dim3(256), 0, stream>>>(qb, kb, vb, rb, mask, zb);

        MGemmArgs<float> go;
        go.A = zb; go.res = srcf;
        go.W[0] = cwo; go.bias[0] = wob + l * D_; go.C[0] = srcf;
        go.W[1] = go.W[0]; go.bias[1] = go.bias[0]; go.C[1] = srcf;
        go.W[2] = go.W[0]; go.bias[2] = go.bias[0]; go.C[2] = srcf;
        go.W[3] = go.W[0]; go.bias[3] = go.bias[0]; go.C[3] = srcf;
        mgemm_k<float><<<dim3(8, 64, 1), dim3(256), 0, stream>>>(go);

        kan_k<<<dim3(NTOK / 4), dim3(256), 0, stream>>>(
            srcf, ln2w + l * D_, ln2b + l * D_, ic + (size_t)l * D_ * 5, zb);

        MGemmArgs<float> gk;
        gk.A = zb; gk.res = srcf;
        gk.W[0] = coc; gk.bias[0] = nullptr; gk.C[0] = srcf;
        gk.W[1] = gk.W[0]; gk.bias[1] = nullptr; gk.C[1] = srcf;
        gk.W[2] = gk.W[0]; gk.bias[2] = nullptr; gk.C[2] = srcf;
        gk.W[3] = gk.W[0]; gk.bias[3] = nullptr; gk.C[3] = srcf;
        mgemm_k<float><<<dim3(8, 64, 1), dim3(256), 0, stream>>>(gk);

        if (l < L_ - 1)
            ln_k<float><<<dim3(NTOK / 4), dim3(256), 0, stream>>>(
                srcf, ln3w + l * D_, ln3b + l * D_, srcf);
        else
            ln_k<float><<<dim3(NTOK / 4), dim3(256), 0, stream>>>(
                srcf, ln3w + l * D_, ln3b + l * D_, out);
    }
}